// Round 10
// baseline (333.712 us; speedup 1.0000x reference)
//
#include <hip/hip_runtime.h>
#include <hip/hip_bf16.h>

#define LRELU(v) ((v) > 0.0f ? (v) : 0.01f * (v))
#define EPS 0.1f

#define BSHIFT  9           // 512-node buckets -> NB ~391 blocks
#define BSIZE   512
#define BIN_EPB 2048        // edges per k_bin block
#define BIN_CAP 6144        // bucket capacity (expected ~4092, wide headroom)
#define CAPP    10240       // per-bucket padded srcs region: BIN_CAP + 512*7 = 9728 <= 10240

typedef __attribute__((ext_vector_type(8))) short bf16x8;
typedef __attribute__((ext_vector_type(4))) float f32x4;

// fast tanh via v_exp_f32 + v_rcp_f32: ~1e-7 abs err, saturates correctly
__device__ __forceinline__ float fast_tanh(float v)
{
    float e = __expf(2.0f * v);
    return 1.0f - 2.0f * __builtin_amdgcn_rcpf(e + 1.0f);
}

__device__ __forceinline__ float bf2f(unsigned short h)
{
    return __uint_as_float(((unsigned int)h) << 16);
}
__device__ __forceinline__ unsigned short f2bf(float f)
{
    unsigned int u = __float_as_uint(f);
    u += 0x7FFFu + ((u >> 16) & 1u);
    return (unsigned short)(u >> 16);
}

// ---------------------------------------------------------------------------
// K1 (r26): all-MFMA feature MLP, block = 64 nodes. k_prep DELETED — the
// 12 KB weight pack now lands in each block's LDS (W reads are L2-broadcast,
// pack VALU hides under input staging; B-fragment reads become ds_read_b128).
// Block 0 also zeroes bucket_cnt (k_bin runs after this kernel completes).
// ---------------------------------------------------------------------------
__global__ void __launch_bounds__(256)
k_feat(const float* __restrict__ num_prop,
       const float* __restrict__ cat_prop,
       const float* __restrict__ W_num, const float* __restrict__ W_cat,
       const float* __restrict__ W_tog,
       const float* __restrict__ b_num, const float* __restrict__ b_cat,
       const float* __restrict__ b_tog,
       const float* __restrict__ att_l, const float* __restrict__ att_r,
       unsigned short* __restrict__ xb,
       float* __restrict__ al, float* __restrict__ ar,
       int* __restrict__ bucket_cnt, int N, int NB)
{
    __shared__ unsigned short in_lds[64][40];   // bf16 inputs (32 used), pad 8
    __shared__ unsigned short mid[64][72];      // bf16 mid, pad 8
    __shared__ unsigned short WbL[8 * 512];     // packed W_tog  (8 KB)
    __shared__ unsigned short Wb1L[4 * 512];    // packed W_num|W_cat (4 KB)

    int tid  = threadIdx.x;
    int lane = tid & 63;
    int w    = tid >> 6;                        // wave 0..3
    int blockStart = blockIdx.x * 64;

    if (blockIdx.x == 0)
        for (int i = tid; i < NB; i += 256) bucket_cnt[i] = 0;

    // weight pack (was k_prep), identical layout
    for (int i = tid; i < 8 * 512; i += 256) {
        int tile = i >> 9;          // kt*4+nt
        int kt   = tile >> 2, nt = tile & 3;
        int ln   = (i >> 3) & 63;
        int j    = i & 7;
        int k    = kt * 32 + (ln >> 4) * 8 + j;
        int n    = nt * 16 + (ln & 15);
        WbL[i] = f2bf(W_tog[k * 64 + n]);
    }
    for (int i = tid; i < 4 * 512; i += 256) {
        int nt   = i >> 9;
        int ln   = (i >> 3) & 63;
        int j    = i & 7;
        int k    = (ln >> 4) * 8 + j;       // 0..31
        int n    = nt * 16 + (ln & 15);     // 0..63
        float wv;
        if (n < 32) wv = (k < 20)  ? W_num[k * 32 + n]              : 0.0f;
        else        wv = (k >= 20) ? W_cat[(k - 20) * 32 + (n - 32)] : 0.0f;
        Wb1L[i] = f2bf(wv);
    }

    for (int i = tid; i < 64 * 20; i += 256) {
        int node = i / 20, k = i % 20;
        int n = min(blockStart + node, N - 1);
        in_lds[node][k] = f2bf(num_prop[(size_t)n * 20 + k]);
    }
    for (int i = tid; i < 64 * 12; i += 256) {
        int node = i / 12, k = i % 12;
        int n = min(blockStart + node, N - 1);
        in_lds[node][20 + k] = f2bf(cat_prop[(size_t)n * 12 + k]);
    }
    __syncthreads();

    int q   = lane >> 4;
    int c16 = lane & 15;

    bf16x8 ain = *(const bf16x8*)&in_lds[w * 16 + c16][q * 8];
    #pragma unroll
    for (int nt = 0; nt < 4; nt++) {
        bf16x8 b = *(const bf16x8*)&Wb1L[nt * 512 + lane * 8];
        f32x4 acc = {0.0f, 0.0f, 0.0f, 0.0f};
        acc = __builtin_amdgcn_mfma_f32_16x16x32_bf16(ain, b, acc, 0, 0, 0);
        int   ch   = nt * 16 + c16;
        float bias = (ch < 32) ? b_num[ch] : b_cat[ch - 32];
        #pragma unroll
        for (int r = 0; r < 4; r++) {
            float s = acc[r] + bias;
            s = LRELU(s);
            mid[w * 16 + q * 4 + r][ch] = f2bf(s);
        }
    }
    __syncthreads();

    bf16x8 a0 = *(const bf16x8*)&mid[w * 16 + c16][q * 8];
    bf16x8 a1 = *(const bf16x8*)&mid[w * 16 + c16][32 + q * 8];

    float pal[4] = {0, 0, 0, 0};
    float par[4] = {0, 0, 0, 0};

    #pragma unroll
    for (int nt = 0; nt < 4; nt++) {
        bf16x8 b0 = *(const bf16x8*)&WbL[(0 * 4 + nt) * 512 + lane * 8];
        bf16x8 b1 = *(const bf16x8*)&WbL[(1 * 4 + nt) * 512 + lane * 8];
        f32x4 acc = {0.0f, 0.0f, 0.0f, 0.0f};
        acc = __builtin_amdgcn_mfma_f32_16x16x32_bf16(a0, b0, acc, 0, 0, 0);
        acc = __builtin_amdgcn_mfma_f32_16x16x32_bf16(a1, b1, acc, 0, 0, 0);

        int   ch  = nt * 16 + c16;
        float bt  = b_tog[ch];
        float atl = att_l[ch];
        float atr = att_r[ch];
        #pragma unroll
        for (int r = 0; r < 4; r++) {
            float s = acc[r] + bt;
            s = LRELU(s);
            int n = blockStart + w * 16 + q * 4 + r;
            if (n < N) xb[(size_t)n * 64 + ch] = f2bf(s);
            pal[r] = fmaf(s, atl, pal[r]);
            par[r] = fmaf(s, atr, par[r]);
        }
    }

    #pragma unroll
    for (int r = 0; r < 4; r++) {
        float pl = pal[r], pr = par[r];
        #pragma unroll
        for (int off = 8; off > 0; off >>= 1) {
            pl += __shfl_xor(pl, off);
            pr += __shfl_xor(pr, off);
        }
        int n = blockStart + w * 16 + q * 4 + r;
        if (c16 == 0 && n < N) { al[n] = pl; ar[n] = pr; }
    }
}

// ---------------------------------------------------------------------------
// K2: radix partition phase 1 (512 threads x 4 edges; no global atomics).
// Bucket entries packed: (src<<9) | (dst & 511).
// ---------------------------------------------------------------------------
__global__ void k_bin(const int* __restrict__ src, const int* __restrict__ dst,
                      int* __restrict__ bucket_cnt,
                      int* __restrict__ buckets, int E, int NB)
{
    __shared__ int  hist[BSIZE];
    __shared__ int  lbase[BSIZE];
    __shared__ int  gbase[BSIZE];
    __shared__ int2 stage[BIN_EPB];

    int tid  = threadIdx.x;          // blockDim = 512
    int base = blockIdx.x * BIN_EPB;

    hist[tid] = 0;
    __syncthreads();

    int s[4], d[4], rk[4];
    #pragma unroll
    for (int k = 0; k < 4; k++) {
        int e = base + k * BSIZE + tid;
        s[k] = -1;
        if (e < E) {
            s[k] = src[e];
            d[k] = dst[e];
            rk[k] = atomicAdd(&hist[d[k] >> BSHIFT], 1);
        }
    }
    __syncthreads();

    int v = hist[tid];
    lbase[tid] = v;
    __syncthreads();
    for (int off = 1; off < BSIZE; off <<= 1) {
        int t = (tid >= off) ? lbase[tid - off] : 0;
        __syncthreads();
        lbase[tid] += t;
        __syncthreads();
    }
    int incl = lbase[tid];
    __syncthreads();
    lbase[tid] = incl - v;
    if (tid < NB && v > 0) gbase[tid] = atomicAdd(&bucket_cnt[tid], v);
    __syncthreads();

    #pragma unroll
    for (int k = 0; k < 4; k++) {
        if (s[k] >= 0) {
            int b = d[k] >> BSHIFT;
            stage[lbase[b] + rk[k]] = make_int2(s[k], d[k]);
        }
    }
    __syncthreads();

    int tot = min(BIN_EPB, E - base);
    for (int i = tid; i < tot; i += BSIZE) {
        int2 p = stage[i];
        int b = p.y >> BSHIFT;
        buckets[(size_t)b * BIN_CAP + gbase[b] + (i - lbase[b])] =
            (p.x << BSHIFT) | (p.y & (BSIZE - 1));
    }
}

// ---------------------------------------------------------------------------
// K2b (r25): FUSED CSR build — histogram + scan + per-node finalize + fill,
// one kernel, bucket staged in LDS. r26: also zeroes x3 (grid-stride),
// replacing the x3 memset dispatch (build completes before gather2).
// ---------------------------------------------------------------------------
__global__ void __launch_bounds__(512)
k_build(const int* __restrict__ buckets, const int* __restrict__ bucket_cnt,
        const float* __restrict__ al, const int* __restrict__ offs,
        float2* __restrict__ ald1,
        int* __restrict__ deg, int* __restrict__ row_start, int* __restrict__ seg,
        int* __restrict__ srcs, float* __restrict__ x3, int N, int U)
{
    __shared__ int stage[BIN_CAP];      // 24 KB
    __shared__ int cnt[BSIZE];
    __shared__ int sc[BSIZE];
    __shared__ int cur[BSIZE];

    int b   = blockIdx.x;
    int tid = threadIdx.x;              // blockDim = 512
    int ecnt = bucket_cnt[b];
    const int* bp = buckets + (size_t)b * BIN_CAP;

    // zero x3 (replaces memset dispatch)
    size_t u64 = (size_t)U * 64;
    for (size_t i = (size_t)b * BSIZE + tid; i < u64; i += (size_t)gridDim.x * BSIZE)
        x3[i] = 0.0f;

    cnt[tid] = 0;
    cur[tid] = 0;
    __syncthreads();

    // histogram + stage bucket into LDS (single global read)
    for (int i = tid; i < ecnt; i += BSIZE) {
        int e = bp[i];
        stage[i] = e;
        atomicAdd(&cnt[e & (BSIZE - 1)], 1);
    }
    __syncthreads();

    // local exclusive scan of padded row lengths
    int d = cnt[tid];
    int p = (d + 7) & ~7;
    sc[tid] = p;
    __syncthreads();
    for (int off = 1; off < BSIZE; off <<= 1) {
        int t = (tid >= off) ? sc[tid - off] : 0;
        __syncthreads();
        sc[tid] += t;
        __syncthreads();
    }
    int rstart = sc[tid] - p;           // local start of this thread's row

    // per-node finalize: deg, row_start, tail-zero, ald1, seg
    int gb = b * CAPP;
    int n  = b * BSIZE + tid;
    if (n < N) {
        deg[n]       = d;
        row_start[n] = gb + rstart;
        for (int k = d; k < p; k++) srcs[gb + rstart + k] = 0;
        float dv = 1.0f / sqrtf((float)d + 1.0f);   // +1 self-loop
        ald1[n] = make_float2(al[n], dv);

        int lo = 0, hi = U;             // first offs[] entry > n
        while (lo < hi) {
            int mid = (lo + hi) >> 1;
            if (offs[mid] <= n) lo = mid + 1; else hi = mid;
        }
        seg[n] = min(max(lo - 1, 0), U - 1);
    }
    __syncthreads();

    // fill srcs from LDS stage via LDS cursors
    for (int i = tid; i < ecnt; i += BSIZE) {
        int e = stage[i];
        int r = e & (BSIZE - 1);
        int o = atomicAdd(&cur[r], 1);
        int rs = sc[r] - ((cnt[r] + 7) & ~7);
        srcs[gb + rs + o] = e >> BSHIFT;
    }
}

// ---------------------------------------------------------------------------
// K5 (r24): gather layer 1, WAVE-PER-4-NODE-CHUNK + lane-parallel in-wave
// alpha. 4 independent rows per wave hide the per-row alpha chain (r22/r23
// comparison). No alphas plumbing anywhere.
// ---------------------------------------------------------------------------
__global__ void k_gather1(const int* __restrict__ srcs,
                          const int* __restrict__ row_start, const int* __restrict__ deg,
                          const unsigned short* __restrict__ xb,
                          const float2* __restrict__ ald1, const float* __restrict__ ar,
                          const float* __restrict__ att_l, const float* __restrict__ att_r,
                          unsigned short* __restrict__ h1b, float2* __restrict__ ald2,
                          float* __restrict__ ar2, int N)
{
    int lane = threadIdx.x & 63;
    int c0   = __builtin_amdgcn_readfirstlane(blockIdx.x * 4 + (threadIdx.x >> 6)) * 4;
    if (c0 >= N) return;
    int nend = min(c0 + 4, N);

    float atl = att_l[lane];
    float atr = att_r[lane];

    for (int n = c0; n < nend; n++) {
        int    s0   = row_start[n];
        int    cnt  = deg[n];
        int    cntp = (cnt + 7) & ~7;
        float2 self = ald1[n];          // {al[n], dinv[n]}
        float  di   = self.y;
        float  arn  = ar[n];

        float acc = 0.0f;
        for (int jb = 0; jb < cntp; jb += 64) {
            // Phase 1: lane-parallel alpha for edges [jb, jb+64)
            float a = 0.0f;
            int   e = jb + lane;
            if (e < cnt) {
                int s = srcs[s0 + e];               // coalesced vector load
                float2 as = ald1[s];                // per-lane 8B gather, L2
                a = fast_tanh(as.x + arn) * as.y * di;
            }
            int te = min(cntp - jb, 64);
            // Phase 2: scalar-offload row gather, alpha via broadcast shfl
            for (int j = 0; j < te; j += 8) {
                int sv[8]; float vv[8];
                #pragma unroll
                for (int t = 0; t < 8; t++) sv[t] = srcs[s0 + jb + j + t];  // scalar
                #pragma unroll
                for (int t = 0; t < 8; t++) vv[t] = bf2f(xb[(size_t)sv[t] * 64 + lane]);
                #pragma unroll
                for (int t = 0; t < 8; t++) acc = fmaf(vv[t], __shfl(a, j + t), acc);
            }
        }

        float selfa = fast_tanh(self.x + arn) * di * di;
        float xnl   = bf2f(xb[(size_t)n * 64 + lane]);
        float v     = acc + (selfa + EPS) * xnl;

        float pl = v * atl;
        float pr = v * atr;
        #pragma unroll
        for (int off = 32; off > 0; off >>= 1) {
            pl += __shfl_down(pl, off);
            pr += __shfl_down(pr, off);
        }
        h1b[(size_t)n * 64 + lane] = f2bf(v);
        if (lane == 0) { ald2[n] = make_float2(pl, di); ar2[n] = pr; }
    }
}

// ---------------------------------------------------------------------------
// K6 (r22): gather layer 2, wave-per-4-node-chunk with register pooling +
// segment-boundary atomic flush + lane-parallel in-wave alpha. 72.5 us.
// ---------------------------------------------------------------------------
__global__ void k_gather2(const int* __restrict__ srcs,
                          const int* __restrict__ row_start, const int* __restrict__ deg,
                          const unsigned short* __restrict__ h1b,
                          const unsigned short* __restrict__ xb,
                          const float2* __restrict__ ald2, const float* __restrict__ ar2,
                          const int* __restrict__ seg,
                          float* __restrict__ x3, int N)
{
    int lane = threadIdx.x & 63;
    int c0   = __builtin_amdgcn_readfirstlane(blockIdx.x * 4 + (threadIdx.x >> 6)) * 4;
    if (c0 >= N) return;
    int nend = min(c0 + 4, N);

    float uacc = 0.0f;
    int   useg = seg[c0];           // wave-uniform

    for (int n = c0; n < nend; n++) {
        int sg = seg[n];            // wave-uniform scalar load
        if (sg != useg) {
            atomicAdd(&x3[(size_t)useg * 64 + lane], uacc);
            uacc = 0.0f;
            useg = sg;
        }

        int    s0   = row_start[n];
        int    cnt  = deg[n];
        int    cntp = (cnt + 7) & ~7;
        float2 self = ald2[n];      // {al2[n], dinv[n]}
        float  di   = self.y;
        float  arn  = ar2[n];

        float acc = 0.0f;
        for (int jb = 0; jb < cntp; jb += 64) {
            float a = 0.0f;
            int   e = jb + lane;
            if (e < cnt) {
                int s = srcs[s0 + e];
                float2 as = ald2[s];
                a = fast_tanh(as.x + arn) * as.y * di;
            }
            int te = min(cntp - jb, 64);
            for (int j = 0; j < te; j += 8) {
                int sv[8]; float vv[8];
                #pragma unroll
                for (int t = 0; t < 8; t++) sv[t] = srcs[s0 + jb + j + t];
                #pragma unroll
                for (int t = 0; t < 8; t++) vv[t] = bf2f(h1b[(size_t)sv[t] * 64 + lane]);
                #pragma unroll
                for (int t = 0; t < 8; t++) acc = fmaf(vv[t], __shfl(a, j + t), acc);
            }
        }

        float selfa = fast_tanh(self.x + arn) * di * di;
        float h1l   = bf2f(h1b[(size_t)n * 64 + lane]);
        float xnl   = bf2f(xb[(size_t)n * 64 + lane]);
        float v = acc + selfa * h1l + EPS * xnl;
        uacc += sqrtf(v * v + 1e-8f);
    }
    atomicAdd(&x3[(size_t)useg * 64 + lane], uacc);
}

// ---------------------------------------------------------------------------
// K8: head (r17 rewrite — 32 register accumulators, weights in LDS).
// ---------------------------------------------------------------------------
__global__ void __launch_bounds__(256)
k_head(const float* __restrict__ x3, const int* __restrict__ re_index,
       const float* __restrict__ W_f1, const float* __restrict__ b_f1,
       const float* __restrict__ W_lab, const float* __restrict__ b_lab,
       float* __restrict__ out, int U)
{
    __shared__ float wf[64][32];    // W_f1 staged: wf[k][j]
    __shared__ float wl[32][2];     // W_lab staged

    int tid = threadIdx.x;
    for (int i = tid; i < 64 * 32; i += 256) wf[i >> 5][i & 31] = W_f1[i];
    if (tid < 64) wl[tid >> 1][tid & 1] = W_lab[tid];
    __syncthreads();

    int u = blockIdx.x * blockDim.x + tid;
    if (u >= U) return;

    int r = re_index[u];
    const float* y = x3 + (size_t)r * 64;

    float s[32];
    #pragma unroll
    for (int j = 0; j < 32; j++) s[j] = b_f1[j];

    for (int k = 0; k < 64; k++) {
        float yk = y[k];
        #pragma unroll
        for (int j = 0; j < 32; j++) s[j] = fmaf(yk, wf[k][j], s[j]);
    }

    float o0 = b_lab[0], o1 = b_lab[1];
    #pragma unroll
    for (int j = 0; j < 32; j++) {
        float t = LRELU(s[j]);
        o0 = fmaf(t, wl[j][0], o0);
        o1 = fmaf(t, wl[j][1], o1);
    }
    out[(size_t)u * 2 + 0] = o0;
    out[(size_t)u * 2 + 1] = o1;
}

// ---------------------------------------------------------------------------
extern "C" void kernel_launch(void* const* d_in, const int* in_sizes, int n_in,
                              void* d_out, int out_size, void* d_ws, size_t ws_size,
                              hipStream_t stream)
{
    const float* num_prop = (const float*)d_in[0];
    const float* cat_prop = (const float*)d_in[1];
    const int*   offs     = (const int*)d_in[2];
    const int*   edge     = (const int*)d_in[3];
    const int*   re_index = (const int*)d_in[4];
    const float* W_num    = (const float*)d_in[5];
    const float* b_num    = (const float*)d_in[6];
    const float* W_cat    = (const float*)d_in[7];
    const float* b_cat    = (const float*)d_in[8];
    const float* W_tog    = (const float*)d_in[9];
    const float* b_tog    = (const float*)d_in[10];
    const float* att_l    = (const float*)d_in[11];
    const float* att_r    = (const float*)d_in[12];
    const float* W_f1     = (const float*)d_in[13];
    const float* b_f1     = (const float*)d_in[14];
    const float* W_lab    = (const float*)d_in[15];
    const float* b_lab    = (const float*)d_in[16];

    const int N = in_sizes[0] / 20;
    const int E = in_sizes[3] / 2;
    const int U = in_sizes[4];

    const int* src = edge;       // edge_index[0]
    const int* dst = edge + E;   // edge_index[1]

    const int NB = (N + BSIZE - 1) >> BSHIFT;          // dst buckets

    // workspace carve-up (4-byte units; float2 8B-aligned by layout)
    float* ws = (float*)d_ws;
    size_t off = 0;
    unsigned short* xb  = (unsigned short*)(ws + off); off += (size_t)N * 32;  // bf16 x
    unsigned short* h1b = (unsigned short*)(ws + off); off += (size_t)N * 32;  // bf16 h1
    float2* ald1 = (float2*)(ws + off); off += (size_t)N * 2;
    float2* ald2 = (float2*)(ws + off); off += (size_t)N * 2;
    int*    buckets = (int*)(ws + off); off += (size_t)NB * BIN_CAP;   // packed entries
    float*  al   = ws + off; off += N;
    float*  ar   = ws + off; off += N;
    float*  ar2  = ws + off; off += N;
    float*  x3   = ws + off; off += (size_t)U * 64;
    int*    deg        = (int*)(ws + off); off += N;
    int*    row_start  = (int*)(ws + off); off += N;
    int*    seg        = (int*)(ws + off); off += N;
    int*    bucket_cnt = (int*)(ws + off); off += NB;
    int*    srcs       = (int*)(ws + off); off += (size_t)NB * CAPP;

    const int nbC   = (N + 15) / 16;        // wave-per-4-node-chunk gathers
    const int nbBin = (E + BIN_EPB - 1) / BIN_EPB;

    // feature MLP (weight pack fused into LDS; block 0 zeroes bucket_cnt)
    k_feat<<<(N + 63) / 64, 256, 0, stream>>>(num_prop, cat_prop,
                                              W_num, W_cat, W_tog,
                                              b_num, b_cat, b_tog,
                                              att_l, att_r, xb, al, ar,
                                              bucket_cnt, N, NB);

    // radix partition phase 1 (packed int entries)
    k_bin<<<nbBin, BSIZE, 0, stream>>>(src, dst, bucket_cnt, buckets, E, NB);

    // fused CSR build (+ x3 zeroing)
    k_build<<<NB, BSIZE, 0, stream>>>(buckets, bucket_cnt, al, offs, ald1,
                                      deg, row_start, seg, srcs, x3, N, U);

    // ---- FAConv layer 1 (h = h0 = x): 4-node chunk, lane-parallel alpha ----
    k_gather1<<<nbC, 256, 0, stream>>>(srcs, row_start, deg, xb, ald1, ar,
                                       att_l, att_r, h1b, ald2, ar2, N);

    // ---- FAConv layer 2 (h = h1, h0 = x): chunked gather, lane-parallel
    //      alpha + boundary-flush pooling ----
    k_gather2<<<nbC, 256, 0, stream>>>(srcs, row_start, deg, h1b, xb,
                                       ald2, ar2, seg, x3, N);

    // ---- head (pooling fused into gather2) ----
    k_head<<<(U + 255) / 256, 256, 0, stream>>>(x3, re_index, W_f1, b_f1, W_lab, b_lab,
                                                (float*)d_out, U);
}

// Round 11
// 324.168 us; speedup vs baseline: 1.0294x; 1.0294x over previous
//
#include <hip/hip_runtime.h>
#include <hip/hip_bf16.h>

#define LRELU(v) ((v) > 0.0f ? (v) : 0.01f * (v))
#define EPS 0.1f

#define BSHIFT  9           // 512-node buckets -> NB ~391 buckets
#define BSIZE   512
#define BIN_EPB 2048        // edges per bin block
#define BIN_CAP 6144        // bucket capacity (expected ~4092, wide headroom)
#define CAPP    10240       // per-bucket padded srcs region: BIN_CAP + 512*7 = 9728 <= 10240

typedef __attribute__((ext_vector_type(8))) short bf16x8;
typedef __attribute__((ext_vector_type(4))) float f32x4;

// fast tanh via v_exp_f32 + v_rcp_f32: ~1e-7 abs err, saturates correctly
__device__ __forceinline__ float fast_tanh(float v)
{
    float e = __expf(2.0f * v);
    return 1.0f - 2.0f * __builtin_amdgcn_rcpf(e + 1.0f);
}

__device__ __forceinline__ float bf2f(unsigned short h)
{
    return __uint_as_float(((unsigned int)h) << 16);
}
__device__ __forceinline__ unsigned short f2bf(float f)
{
    unsigned int u = __float_as_uint(f);
    u += 0x7FFFu + ((u >> 16) & 1u);
    return (unsigned short)(u >> 16);
}

// ---------------------------------------------------------------------------
// K0: pack weights into bf16 MFMA B-fragment order (r15/r16-verified;
// restored as a separate kernel — r26's in-feat pack cut feat occupancy
// 8->6 blocks/CU and regressed).
// ---------------------------------------------------------------------------
__global__ void k_prep(const float* __restrict__ W_num, const float* __restrict__ W_cat,
                       const float* __restrict__ W_tog,
                       unsigned short* __restrict__ Wb, unsigned short* __restrict__ Wb1)
{
    int t = threadIdx.x;            // one block, 256 threads
    for (int i = t; i < 8 * 512; i += 256) {
        int tile = i >> 9;          // kt*4+nt
        int kt   = tile >> 2, nt = tile & 3;
        int lane = (i >> 3) & 63;
        int j    = i & 7;
        int k    = kt * 32 + (lane >> 4) * 8 + j;
        int n    = nt * 16 + (lane & 15);
        Wb[i] = f2bf(W_tog[k * 64 + n]);
    }
    for (int i = t; i < 4 * 512; i += 256) {
        int nt   = i >> 9;
        int lane = (i >> 3) & 63;
        int j    = i & 7;
        int k    = (lane >> 4) * 8 + j;     // 0..31
        int n    = nt * 16 + (lane & 15);   // 0..63
        float w;
        if (n < 32) w = (k < 20)  ? W_num[k * 32 + n]              : 0.0f;
        else        w = (k >= 20) ? W_cat[(k - 20) * 32 + (n - 32)] : 0.0f;
        Wb1[i] = f2bf(w);
    }
}

// ---------------------------------------------------------------------------
// K1+K2 (r27): FUSED heterogeneous-grid kernel. feat and bin are data-
// independent (feat: node props -> xb/al/ar; bin: edges -> buckets) but were
// serialized on the single stream. Blocks [0, nbBin) run the bin body (all
// 782 fit resident at once); blocks [nbBin, ..) run feat widened to 128
// nodes / 512 threads (LDS 28.7 KB -> 4 blocks/CU x 128 = 512 resident
// nodes/CU, same as r25's 8 x 64). The two workloads overlap on different
// bottlenecks (bin: LDS atomics+barriers; feat: MFMA + streaming).
// ---------------------------------------------------------------------------
__global__ void __launch_bounds__(512)
k_featbin(// feat args
          const float* __restrict__ num_prop, const float* __restrict__ cat_prop,
          const unsigned short* __restrict__ Wb1, const float* __restrict__ b_num,
          const float* __restrict__ b_cat, const unsigned short* __restrict__ Wb,
          const float* __restrict__ b_tog, const float* __restrict__ att_l,
          const float* __restrict__ att_r, unsigned short* __restrict__ xb,
          float* __restrict__ al, float* __restrict__ ar,
          // bin args
          const int* __restrict__ src, const int* __restrict__ dst,
          int* __restrict__ bucket_cnt, int* __restrict__ buckets,
          int nbBin, int N, int E, int NB)
{
    __shared__ __align__(16) char shmem[28672];

    int tid = threadIdx.x;          // blockDim = 512

    if ((int)blockIdx.x < nbBin) {
        // ================= bin body (identical to r25 k_bin) =================
        int*  hist  = (int*)shmem;                  //  2 KB
        int*  lbase = hist + BSIZE;                 //  2 KB
        int*  gbase = lbase + BSIZE;                //  2 KB
        int2* stage = (int2*)(gbase + BSIZE);       // 16 KB (offset 6144, 8B-aligned)

        int base = blockIdx.x * BIN_EPB;

        hist[tid] = 0;
        __syncthreads();

        int s[4], d[4], rk[4];
        #pragma unroll
        for (int k = 0; k < 4; k++) {
            int e = base + k * BSIZE + tid;
            s[k] = -1;
            if (e < E) {
                s[k] = src[e];
                d[k] = dst[e];
                rk[k] = atomicAdd(&hist[d[k] >> BSHIFT], 1);
            }
        }
        __syncthreads();

        int v = hist[tid];
        lbase[tid] = v;
        __syncthreads();
        for (int off = 1; off < BSIZE; off <<= 1) {
            int t = (tid >= off) ? lbase[tid - off] : 0;
            __syncthreads();
            lbase[tid] += t;
            __syncthreads();
        }
        int incl = lbase[tid];
        __syncthreads();
        lbase[tid] = incl - v;
        if (tid < NB && v > 0) gbase[tid] = atomicAdd(&bucket_cnt[tid], v);
        __syncthreads();

        #pragma unroll
        for (int k = 0; k < 4; k++) {
            if (s[k] >= 0) {
                int b = d[k] >> BSHIFT;
                stage[lbase[b] + rk[k]] = make_int2(s[k], d[k]);
            }
        }
        __syncthreads();

        int tot = min(BIN_EPB, E - base);
        for (int i = tid; i < tot; i += BSIZE) {
            int2 p = stage[i];
            int b = p.y >> BSHIFT;
            buckets[(size_t)b * BIN_CAP + gbase[b] + (i - lbase[b])] =
                (p.x << BSHIFT) | (p.y & (BSIZE - 1));
        }
    } else {
        // ================= feat body: 128 nodes, 8 waves =================
        unsigned short (*in_lds)[40] = (unsigned short(*)[40])shmem;            // 10.0 KB
        unsigned short (*mid)[72]    = (unsigned short(*)[72])(shmem + 10240);  // 18.4 KB

        int lane = tid & 63;
        int w    = tid >> 6;                        // wave 0..7
        int blockStart = (blockIdx.x - nbBin) * 128;

        for (int i = tid; i < 128 * 20; i += 512) {
            int node = i / 20, k = i % 20;
            int n = min(blockStart + node, N - 1);
            in_lds[node][k] = f2bf(num_prop[(size_t)n * 20 + k]);
        }
        for (int i = tid; i < 128 * 12; i += 512) {
            int node = i / 12, k = i % 12;
            int n = min(blockStart + node, N - 1);
            in_lds[node][20 + k] = f2bf(cat_prop[(size_t)n * 12 + k]);
        }
        __syncthreads();

        int q   = lane >> 4;
        int c16 = lane & 15;

        bf16x8 ain = *(const bf16x8*)&in_lds[w * 16 + c16][q * 8];
        #pragma unroll
        for (int nt = 0; nt < 4; nt++) {
            bf16x8 b = *(const bf16x8*)&Wb1[nt * 512 + lane * 8];
            f32x4 acc = {0.0f, 0.0f, 0.0f, 0.0f};
            acc = __builtin_amdgcn_mfma_f32_16x16x32_bf16(ain, b, acc, 0, 0, 0);
            int   ch   = nt * 16 + c16;
            float bias = (ch < 32) ? b_num[ch] : b_cat[ch - 32];
            #pragma unroll
            for (int r = 0; r < 4; r++) {
                float s = acc[r] + bias;
                s = LRELU(s);
                mid[w * 16 + q * 4 + r][ch] = f2bf(s);
            }
        }
        // intra-wave LDS dependency only (wave w writes/reads rows w*16..w*16+15)

        bf16x8 a0 = *(const bf16x8*)&mid[w * 16 + c16][q * 8];
        bf16x8 a1 = *(const bf16x8*)&mid[w * 16 + c16][32 + q * 8];

        float pal[4] = {0, 0, 0, 0};
        float par[4] = {0, 0, 0, 0};

        #pragma unroll
        for (int nt = 0; nt < 4; nt++) {
            bf16x8 b0 = *(const bf16x8*)&Wb[(0 * 4 + nt) * 512 + lane * 8];
            bf16x8 b1 = *(const bf16x8*)&Wb[(1 * 4 + nt) * 512 + lane * 8];
            f32x4 acc = {0.0f, 0.0f, 0.0f, 0.0f};
            acc = __builtin_amdgcn_mfma_f32_16x16x32_bf16(a0, b0, acc, 0, 0, 0);
            acc = __builtin_amdgcn_mfma_f32_16x16x32_bf16(a1, b1, acc, 0, 0, 0);

            int   ch  = nt * 16 + c16;
            float bt  = b_tog[ch];
            float atl = att_l[ch];
            float atr = att_r[ch];
            #pragma unroll
            for (int r = 0; r < 4; r++) {
                float s = acc[r] + bt;
                s = LRELU(s);
                int n = blockStart + w * 16 + q * 4 + r;
                if (n < N) xb[(size_t)n * 64 + ch] = f2bf(s);
                pal[r] = fmaf(s, atl, pal[r]);
                par[r] = fmaf(s, atr, par[r]);
            }
        }

        #pragma unroll
        for (int r = 0; r < 4; r++) {
            float pl = pal[r], pr = par[r];
            #pragma unroll
            for (int off = 8; off > 0; off >>= 1) {
                pl += __shfl_xor(pl, off);
                pr += __shfl_xor(pr, off);
            }
            int n = blockStart + w * 16 + q * 4 + r;
            if (c16 == 0 && n < N) { al[n] = pl; ar[n] = pr; }
        }
    }
}

// ---------------------------------------------------------------------------
// K2b (r25): FUSED CSR build — histogram + scan + per-node finalize + fill,
// one kernel, bucket staged in LDS.
// ---------------------------------------------------------------------------
__global__ void __launch_bounds__(512)
k_build(const int* __restrict__ buckets, const int* __restrict__ bucket_cnt,
        const float* __restrict__ al, const int* __restrict__ offs,
        float2* __restrict__ ald1,
        int* __restrict__ deg, int* __restrict__ row_start, int* __restrict__ seg,
        int* __restrict__ srcs, int N, int U)
{
    __shared__ int stage[BIN_CAP];      // 24 KB
    __shared__ int cnt[BSIZE];
    __shared__ int sc[BSIZE];
    __shared__ int cur[BSIZE];

    int b   = blockIdx.x;
    int tid = threadIdx.x;              // blockDim = 512
    int ecnt = bucket_cnt[b];
    const int* bp = buckets + (size_t)b * BIN_CAP;

    cnt[tid] = 0;
    cur[tid] = 0;
    __syncthreads();

    // histogram + stage bucket into LDS (single global read)
    for (int i = tid; i < ecnt; i += BSIZE) {
        int e = bp[i];
        stage[i] = e;
        atomicAdd(&cnt[e & (BSIZE - 1)], 1);
    }
    __syncthreads();

    // local exclusive scan of padded row lengths
    int d = cnt[tid];
    int p = (d + 7) & ~7;
    sc[tid] = p;
    __syncthreads();
    for (int off = 1; off < BSIZE; off <<= 1) {
        int t = (tid >= off) ? sc[tid - off] : 0;
        __syncthreads();
        sc[tid] += t;
        __syncthreads();
    }
    int rstart = sc[tid] - p;           // local start of this thread's row

    // per-node finalize: deg, row_start, tail-zero, ald1, seg
    int gb = b * CAPP;
    int n  = b * BSIZE + tid;
    if (n < N) {
        deg[n]       = d;
        row_start[n] = gb + rstart;
        for (int k = d; k < p; k++) srcs[gb + rstart + k] = 0;
        float dv = 1.0f / sqrtf((float)d + 1.0f);   // +1 self-loop
        ald1[n] = make_float2(al[n], dv);

        int lo = 0, hi = U;             // first offs[] entry > n
        while (lo < hi) {
            int mid = (lo + hi) >> 1;
            if (offs[mid] <= n) lo = mid + 1; else hi = mid;
        }
        seg[n] = min(max(lo - 1, 0), U - 1);
    }
    __syncthreads();

    // fill srcs from LDS stage via LDS cursors
    for (int i = tid; i < ecnt; i += BSIZE) {
        int e = stage[i];
        int r = e & (BSIZE - 1);
        int o = atomicAdd(&cur[r], 1);
        int rs = sc[r] - ((cnt[r] + 7) & ~7);
        srcs[gb + rs + o] = e >> BSHIFT;
    }
}

// ---------------------------------------------------------------------------
// K5 (r24): gather layer 1, WAVE-PER-4-NODE-CHUNK + lane-parallel in-wave
// alpha. 4 independent rows per wave hide the per-row alpha chain (r22/r23
// comparison). No alphas plumbing anywhere.
// ---------------------------------------------------------------------------
__global__ void k_gather1(const int* __restrict__ srcs,
                          const int* __restrict__ row_start, const int* __restrict__ deg,
                          const unsigned short* __restrict__ xb,
                          const float2* __restrict__ ald1, const float* __restrict__ ar,
                          const float* __restrict__ att_l, const float* __restrict__ att_r,
                          unsigned short* __restrict__ h1b, float2* __restrict__ ald2,
                          float* __restrict__ ar2, int N)
{
    int lane = threadIdx.x & 63;
    int c0   = __builtin_amdgcn_readfirstlane(blockIdx.x * 4 + (threadIdx.x >> 6)) * 4;
    if (c0 >= N) return;
    int nend = min(c0 + 4, N);

    float atl = att_l[lane];
    float atr = att_r[lane];

    for (int n = c0; n < nend; n++) {
        int    s0   = row_start[n];
        int    cnt  = deg[n];
        int    cntp = (cnt + 7) & ~7;
        float2 self = ald1[n];          // {al[n], dinv[n]}
        float  di   = self.y;
        float  arn  = ar[n];

        float acc = 0.0f;
        for (int jb = 0; jb < cntp; jb += 64) {
            // Phase 1: lane-parallel alpha for edges [jb, jb+64)
            float a = 0.0f;
            int   e = jb + lane;
            if (e < cnt) {
                int s = srcs[s0 + e];               // coalesced vector load
                float2 as = ald1[s];                // per-lane 8B gather, L2
                a = fast_tanh(as.x + arn) * as.y * di;
            }
            int te = min(cntp - jb, 64);
            // Phase 2: scalar-offload row gather, alpha via broadcast shfl
            for (int j = 0; j < te; j += 8) {
                int sv[8]; float vv[8];
                #pragma unroll
                for (int t = 0; t < 8; t++) sv[t] = srcs[s0 + jb + j + t];  // scalar
                #pragma unroll
                for (int t = 0; t < 8; t++) vv[t] = bf2f(xb[(size_t)sv[t] * 64 + lane]);
                #pragma unroll
                for (int t = 0; t < 8; t++) acc = fmaf(vv[t], __shfl(a, j + t), acc);
            }
        }

        float selfa = fast_tanh(self.x + arn) * di * di;
        float xnl   = bf2f(xb[(size_t)n * 64 + lane]);
        float v     = acc + (selfa + EPS) * xnl;

        float pl = v * atl;
        float pr = v * atr;
        #pragma unroll
        for (int off = 32; off > 0; off >>= 1) {
            pl += __shfl_down(pl, off);
            pr += __shfl_down(pr, off);
        }
        h1b[(size_t)n * 64 + lane] = f2bf(v);
        if (lane == 0) { ald2[n] = make_float2(pl, di); ar2[n] = pr; }
    }
}

// ---------------------------------------------------------------------------
// K6 (r22): gather layer 2, wave-per-4-node-chunk with register pooling +
// segment-boundary atomic flush + lane-parallel in-wave alpha. 72.5 us.
// ---------------------------------------------------------------------------
__global__ void k_gather2(const int* __restrict__ srcs,
                          const int* __restrict__ row_start, const int* __restrict__ deg,
                          const unsigned short* __restrict__ h1b,
                          const unsigned short* __restrict__ xb,
                          const float2* __restrict__ ald2, const float* __restrict__ ar2,
                          const int* __restrict__ seg,
                          float* __restrict__ x3, int N)
{
    int lane = threadIdx.x & 63;
    int c0   = __builtin_amdgcn_readfirstlane(blockIdx.x * 4 + (threadIdx.x >> 6)) * 4;
    if (c0 >= N) return;
    int nend = min(c0 + 4, N);

    float uacc = 0.0f;
    int   useg = seg[c0];           // wave-uniform

    for (int n = c0; n < nend; n++) {
        int sg = seg[n];            // wave-uniform scalar load
        if (sg != useg) {
            atomicAdd(&x3[(size_t)useg * 64 + lane], uacc);
            uacc = 0.0f;
            useg = sg;
        }

        int    s0   = row_start[n];
        int    cnt  = deg[n];
        int    cntp = (cnt + 7) & ~7;
        float2 self = ald2[n];      // {al2[n], dinv[n]}
        float  di   = self.y;
        float  arn  = ar2[n];

        float acc = 0.0f;
        for (int jb = 0; jb < cntp; jb += 64) {
            float a = 0.0f;
            int   e = jb + lane;
            if (e < cnt) {
                int s = srcs[s0 + e];
                float2 as = ald2[s];
                a = fast_tanh(as.x + arn) * as.y * di;
            }
            int te = min(cntp - jb, 64);
            for (int j = 0; j < te; j += 8) {
                int sv[8]; float vv[8];
                #pragma unroll
                for (int t = 0; t < 8; t++) sv[t] = srcs[s0 + jb + j + t];
                #pragma unroll
                for (int t = 0; t < 8; t++) vv[t] = bf2f(h1b[(size_t)sv[t] * 64 + lane]);
                #pragma unroll
                for (int t = 0; t < 8; t++) acc = fmaf(vv[t], __shfl(a, j + t), acc);
            }
        }

        float selfa = fast_tanh(self.x + arn) * di * di;
        float h1l   = bf2f(h1b[(size_t)n * 64 + lane]);
        float xnl   = bf2f(xb[(size_t)n * 64 + lane]);
        float v = acc + selfa * h1l + EPS * xnl;
        uacc += sqrtf(v * v + 1e-8f);
    }
    atomicAdd(&x3[(size_t)useg * 64 + lane], uacc);
}

// ---------------------------------------------------------------------------
// K8: head (r17 rewrite — 32 register accumulators, weights in LDS).
// ---------------------------------------------------------------------------
__global__ void __launch_bounds__(256)
k_head(const float* __restrict__ x3, const int* __restrict__ re_index,
       const float* __restrict__ W_f1, const float* __restrict__ b_f1,
       const float* __restrict__ W_lab, const float* __restrict__ b_lab,
       float* __restrict__ out, int U)
{
    __shared__ float wf[64][32];    // W_f1 staged: wf[k][j]
    __shared__ float wl[32][2];     // W_lab staged

    int tid = threadIdx.x;
    for (int i = tid; i < 64 * 32; i += 256) wf[i >> 5][i & 31] = W_f1[i];
    if (tid < 64) wl[tid >> 1][tid & 1] = W_lab[tid];
    __syncthreads();

    int u = blockIdx.x * blockDim.x + tid;
    if (u >= U) return;

    int r = re_index[u];
    const float* y = x3 + (size_t)r * 64;

    float s[32];
    #pragma unroll
    for (int j = 0; j < 32; j++) s[j] = b_f1[j];

    for (int k = 0; k < 64; k++) {
        float yk = y[k];
        #pragma unroll
        for (int j = 0; j < 32; j++) s[j] = fmaf(yk, wf[k][j], s[j]);
    }

    float o0 = b_lab[0], o1 = b_lab[1];
    #pragma unroll
    for (int j = 0; j < 32; j++) {
        float t = LRELU(s[j]);
        o0 = fmaf(t, wl[j][0], o0);
        o1 = fmaf(t, wl[j][1], o1);
    }
    out[(size_t)u * 2 + 0] = o0;
    out[(size_t)u * 2 + 1] = o1;
}

// ---------------------------------------------------------------------------
extern "C" void kernel_launch(void* const* d_in, const int* in_sizes, int n_in,
                              void* d_out, int out_size, void* d_ws, size_t ws_size,
                              hipStream_t stream)
{
    const float* num_prop = (const float*)d_in[0];
    const float* cat_prop = (const float*)d_in[1];
    const int*   offs     = (const int*)d_in[2];
    const int*   edge     = (const int*)d_in[3];
    const int*   re_index = (const int*)d_in[4];
    const float* W_num    = (const float*)d_in[5];
    const float* b_num    = (const float*)d_in[6];
    const float* W_cat    = (const float*)d_in[7];
    const float* b_cat    = (const float*)d_in[8];
    const float* W_tog    = (const float*)d_in[9];
    const float* b_tog    = (const float*)d_in[10];
    const float* att_l    = (const float*)d_in[11];
    const float* att_r    = (const float*)d_in[12];
    const float* W_f1     = (const float*)d_in[13];
    const float* b_f1     = (const float*)d_in[14];
    const float* W_lab    = (const float*)d_in[15];
    const float* b_lab    = (const float*)d_in[16];

    const int N = in_sizes[0] / 20;
    const int E = in_sizes[3] / 2;
    const int U = in_sizes[4];

    const int* src = edge;       // edge_index[0]
    const int* dst = edge + E;   // edge_index[1]

    const int NB = (N + BSIZE - 1) >> BSHIFT;          // dst buckets

    // workspace carve-up (4-byte units; float2 8B-aligned by layout)
    float* ws = (float*)d_ws;
    size_t off = 0;
    unsigned short* xb  = (unsigned short*)(ws + off); off += (size_t)N * 32;  // bf16 x
    unsigned short* h1b = (unsigned short*)(ws + off); off += (size_t)N * 32;  // bf16 h1
    float2* ald1 = (float2*)(ws + off); off += (size_t)N * 2;
    float2* ald2 = (float2*)(ws + off); off += (size_t)N * 2;
    int*    buckets = (int*)(ws + off); off += (size_t)NB * BIN_CAP;   // packed entries
    float*  al   = ws + off; off += N;
    float*  ar   = ws + off; off += N;
    float*  ar2  = ws + off; off += N;
    float*  x3   = ws + off; off += (size_t)U * 64;
    unsigned short* Wb  = (unsigned short*)(ws + off); off += 2048;  // 4096 bf16
    unsigned short* Wb1 = (unsigned short*)(ws + off); off += 1024;  // 2048 bf16
    int*    deg        = (int*)(ws + off); off += N;
    int*    row_start  = (int*)(ws + off); off += N;
    int*    seg        = (int*)(ws + off); off += N;
    int*    bucket_cnt = (int*)(ws + off); off += NB;
    int*    srcs       = (int*)(ws + off); off += (size_t)NB * CAPP;

    hipMemsetAsync(bucket_cnt, 0, (size_t)NB * 4, stream);
    hipMemsetAsync(x3, 0, (size_t)U * 64 * 4, stream);   // gather2 flushes atomically

    const int nbC    = (N + 15) / 16;       // wave-per-4-node-chunk gathers
    const int nbBin  = (E + BIN_EPB - 1) / BIN_EPB;
    const int nbFeat = (N + 127) / 128;     // 128-node feat blocks

    // pack both weight matrices into MFMA B-fragment bf16 layout
    k_prep<<<1, 256, 0, stream>>>(W_num, W_cat, W_tog, Wb, Wb1);

    // fused feat (128-node) + bin: bin blocks first, feat fills the rest
    k_featbin<<<nbBin + nbFeat, 512, 0, stream>>>(num_prop, cat_prop, Wb1, b_num,
                                                  b_cat, Wb, b_tog, att_l, att_r,
                                                  xb, al, ar,
                                                  src, dst, bucket_cnt, buckets,
                                                  nbBin, N, E, NB);

    // fused CSR build
    k_build<<<NB, BSIZE, 0, stream>>>(buckets, bucket_cnt, al, offs, ald1,
                                      deg, row_start, seg, srcs, N, U);

    // ---- FAConv layer 1 (h = h0 = x): 4-node chunk, lane-parallel alpha ----
    k_gather1<<<nbC, 256, 0, stream>>>(srcs, row_start, deg, xb, ald1, ar,
                                       att_l, att_r, h1b, ald2, ar2, N);

    // ---- FAConv layer 2 (h = h1, h0 = x): chunked gather, lane-parallel
    //      alpha + boundary-flush pooling ----
    k_gather2<<<nbC, 256, 0, stream>>>(srcs, row_start, deg, h1b, xb,
                                       ald2, ar2, seg, x3, N);

    // ---- head (pooling fused into gather2) ----
    k_head<<<(U + 255) / 256, 256, 0, stream>>>(x3, re_index, W_f1, b_f1, W_lab, b_lab,
                                                (float*)d_out, U);
}

// Round 12
// 322.933 us; speedup vs baseline: 1.0334x; 1.0038x over previous
//
#include <hip/hip_runtime.h>
#include <hip/hip_bf16.h>

#define LRELU(v) ((v) > 0.0f ? (v) : 0.01f * (v))
#define EPS 0.1f

#define BSHIFT  9           // 512-node buckets -> NB ~391 buckets
#define BSIZE   512
#define BIN_EPB 2048        // edges per bin block
#define BIN_CAP 6144        // bucket capacity (expected ~4092, wide headroom)
#define CAPP    10240       // per-bucket padded srcs region: BIN_CAP + 512*7 = 9728 <= 10240
#define CHUNK   8           // nodes per wave in the gathers (r28: 4 -> 8)

typedef __attribute__((ext_vector_type(8))) short bf16x8;
typedef __attribute__((ext_vector_type(4))) float f32x4;

// fast tanh via v_exp_f32 + v_rcp_f32: ~1e-7 abs err, saturates correctly
__device__ __forceinline__ float fast_tanh(float v)
{
    float e = __expf(2.0f * v);
    return 1.0f - 2.0f * __builtin_amdgcn_rcpf(e + 1.0f);
}

__device__ __forceinline__ float bf2f(unsigned short h)
{
    return __uint_as_float(((unsigned int)h) << 16);
}
__device__ __forceinline__ unsigned short f2bf(float f)
{
    unsigned int u = __float_as_uint(f);
    u += 0x7FFFu + ((u >> 16) & 1u);
    return (unsigned short)(u >> 16);
}

// ---------------------------------------------------------------------------
// K0: pack weights into bf16 MFMA B-fragment order (r15/r16-verified).
// r28: also zeroes bucket_cnt (runs before featbin; kills one memset).
// ---------------------------------------------------------------------------
__global__ void k_prep(const float* __restrict__ W_num, const float* __restrict__ W_cat,
                       const float* __restrict__ W_tog,
                       unsigned short* __restrict__ Wb, unsigned short* __restrict__ Wb1,
                       int* __restrict__ bucket_cnt, int NB)
{
    int t = threadIdx.x;            // one block, 256 threads
    for (int i = t; i < NB; i += 256) bucket_cnt[i] = 0;
    for (int i = t; i < 8 * 512; i += 256) {
        int tile = i >> 9;          // kt*4+nt
        int kt   = tile >> 2, nt = tile & 3;
        int lane = (i >> 3) & 63;
        int j    = i & 7;
        int k    = kt * 32 + (lane >> 4) * 8 + j;
        int n    = nt * 16 + (lane & 15);
        Wb[i] = f2bf(W_tog[k * 64 + n]);
    }
    for (int i = t; i < 4 * 512; i += 256) {
        int nt   = i >> 9;
        int lane = (i >> 3) & 63;
        int j    = i & 7;
        int k    = (lane >> 4) * 8 + j;     // 0..31
        int n    = nt * 16 + (lane & 15);   // 0..63
        float w;
        if (n < 32) w = (k < 20)  ? W_num[k * 32 + n]              : 0.0f;
        else        w = (k >= 20) ? W_cat[(k - 20) * 32 + (n - 32)] : 0.0f;
        Wb1[i] = f2bf(w);
    }
}

// ---------------------------------------------------------------------------
// K1+K2 (r27, kept): FUSED heterogeneous-grid kernel — bin blocks first,
// feat (128-node / 8-wave) blocks fill the remaining slots and overlap.
// ---------------------------------------------------------------------------
__global__ void __launch_bounds__(512)
k_featbin(// feat args
          const float* __restrict__ num_prop, const float* __restrict__ cat_prop,
          const unsigned short* __restrict__ Wb1, const float* __restrict__ b_num,
          const float* __restrict__ b_cat, const unsigned short* __restrict__ Wb,
          const float* __restrict__ b_tog, const float* __restrict__ att_l,
          const float* __restrict__ att_r, unsigned short* __restrict__ xb,
          float* __restrict__ al, float* __restrict__ ar,
          // bin args
          const int* __restrict__ src, const int* __restrict__ dst,
          int* __restrict__ bucket_cnt, int* __restrict__ buckets,
          int nbBin, int N, int E, int NB)
{
    __shared__ __align__(16) char shmem[28672];

    int tid = threadIdx.x;          // blockDim = 512

    if ((int)blockIdx.x < nbBin) {
        // ================= bin body =================
        int*  hist  = (int*)shmem;                  //  2 KB
        int*  lbase = hist + BSIZE;                 //  2 KB
        int*  gbase = lbase + BSIZE;                //  2 KB
        int2* stage = (int2*)(gbase + BSIZE);       // 16 KB

        int base = blockIdx.x * BIN_EPB;

        hist[tid] = 0;
        __syncthreads();

        int s[4], d[4], rk[4];
        #pragma unroll
        for (int k = 0; k < 4; k++) {
            int e = base + k * BSIZE + tid;
            s[k] = -1;
            if (e < E) {
                s[k] = src[e];
                d[k] = dst[e];
                rk[k] = atomicAdd(&hist[d[k] >> BSHIFT], 1);
            }
        }
        __syncthreads();

        int v = hist[tid];
        lbase[tid] = v;
        __syncthreads();
        for (int off = 1; off < BSIZE; off <<= 1) {
            int t = (tid >= off) ? lbase[tid - off] : 0;
            __syncthreads();
            lbase[tid] += t;
            __syncthreads();
        }
        int incl = lbase[tid];
        __syncthreads();
        lbase[tid] = incl - v;
        if (tid < NB && v > 0) gbase[tid] = atomicAdd(&bucket_cnt[tid], v);
        __syncthreads();

        #pragma unroll
        for (int k = 0; k < 4; k++) {
            if (s[k] >= 0) {
                int b = d[k] >> BSHIFT;
                stage[lbase[b] + rk[k]] = make_int2(s[k], d[k]);
            }
        }
        __syncthreads();

        int tot = min(BIN_EPB, E - base);
        for (int i = tid; i < tot; i += BSIZE) {
            int2 p = stage[i];
            int b = p.y >> BSHIFT;
            buckets[(size_t)b * BIN_CAP + gbase[b] + (i - lbase[b])] =
                (p.x << BSHIFT) | (p.y & (BSIZE - 1));
        }
    } else {
        // ================= feat body: 128 nodes, 8 waves =================
        unsigned short (*in_lds)[40] = (unsigned short(*)[40])shmem;            // 10.0 KB
        unsigned short (*mid)[72]    = (unsigned short(*)[72])(shmem + 10240);  // 18.4 KB

        int lane = tid & 63;
        int w    = tid >> 6;                        // wave 0..7
        int blockStart = (blockIdx.x - nbBin) * 128;

        for (int i = tid; i < 128 * 20; i += 512) {
            int node = i / 20, k = i % 20;
            int n = min(blockStart + node, N - 1);
            in_lds[node][k] = f2bf(num_prop[(size_t)n * 20 + k]);
        }
        for (int i = tid; i < 128 * 12; i += 512) {
            int node = i / 12, k = i % 12;
            int n = min(blockStart + node, N - 1);
            in_lds[node][20 + k] = f2bf(cat_prop[(size_t)n * 12 + k]);
        }
        __syncthreads();

        int q   = lane >> 4;
        int c16 = lane & 15;

        bf16x8 ain = *(const bf16x8*)&in_lds[w * 16 + c16][q * 8];
        #pragma unroll
        for (int nt = 0; nt < 4; nt++) {
            bf16x8 b = *(const bf16x8*)&Wb1[nt * 512 + lane * 8];
            f32x4 acc = {0.0f, 0.0f, 0.0f, 0.0f};
            acc = __builtin_amdgcn_mfma_f32_16x16x32_bf16(ain, b, acc, 0, 0, 0);
            int   ch   = nt * 16 + c16;
            float bias = (ch < 32) ? b_num[ch] : b_cat[ch - 32];
            #pragma unroll
            for (int r = 0; r < 4; r++) {
                float s = acc[r] + bias;
                s = LRELU(s);
                mid[w * 16 + q * 4 + r][ch] = f2bf(s);
            }
        }
        // intra-wave LDS dependency only (wave w writes/reads rows w*16..w*16+15)

        bf16x8 a0 = *(const bf16x8*)&mid[w * 16 + c16][q * 8];
        bf16x8 a1 = *(const bf16x8*)&mid[w * 16 + c16][32 + q * 8];

        float pal[4] = {0, 0, 0, 0};
        float par[4] = {0, 0, 0, 0};

        #pragma unroll
        for (int nt = 0; nt < 4; nt++) {
            bf16x8 b0 = *(const bf16x8*)&Wb[(0 * 4 + nt) * 512 + lane * 8];
            bf16x8 b1 = *(const bf16x8*)&Wb[(1 * 4 + nt) * 512 + lane * 8];
            f32x4 acc = {0.0f, 0.0f, 0.0f, 0.0f};
            acc = __builtin_amdgcn_mfma_f32_16x16x32_bf16(a0, b0, acc, 0, 0, 0);
            acc = __builtin_amdgcn_mfma_f32_16x16x32_bf16(a1, b1, acc, 0, 0, 0);

            int   ch  = nt * 16 + c16;
            float bt  = b_tog[ch];
            float atl = att_l[ch];
            float atr = att_r[ch];
            #pragma unroll
            for (int r = 0; r < 4; r++) {
                float s = acc[r] + bt;
                s = LRELU(s);
                int n = blockStart + w * 16 + q * 4 + r;
                if (n < N) xb[(size_t)n * 64 + ch] = f2bf(s);
                pal[r] = fmaf(s, atl, pal[r]);
                par[r] = fmaf(s, atr, par[r]);
            }
        }

        #pragma unroll
        for (int r = 0; r < 4; r++) {
            float pl = pal[r], pr = par[r];
            #pragma unroll
            for (int off = 8; off > 0; off >>= 1) {
                pl += __shfl_xor(pl, off);
                pr += __shfl_xor(pr, off);
            }
            int n = blockStart + w * 16 + q * 4 + r;
            if (c16 == 0 && n < N) { al[n] = pl; ar[n] = pr; }
        }
    }
}

// ---------------------------------------------------------------------------
// K2b (r25/r28): FUSED CSR build. r28: packs {row_start,deg} into rd[n]
// (one 8B scalar load per node in the gathers) and {al,dinv,ar} into
// aldr1[n] float4 (one 16B self load; per-lane alpha gather reads only the
// leading float2 — same line traffic). Also zeroes x3 (kills the memset).
// ---------------------------------------------------------------------------
__global__ void __launch_bounds__(512)
k_build(const int* __restrict__ buckets, const int* __restrict__ bucket_cnt,
        const float* __restrict__ al, const float* __restrict__ ar,
        const int* __restrict__ offs,
        float4* __restrict__ aldr1,
        int2* __restrict__ rd, int* __restrict__ seg,
        int* __restrict__ srcs, float* __restrict__ x3, int N, int U)
{
    __shared__ int stage[BIN_CAP];      // 24 KB
    __shared__ int cnt[BSIZE];
    __shared__ int sc[BSIZE];
    __shared__ int cur[BSIZE];

    int b   = blockIdx.x;
    int tid = threadIdx.x;              // blockDim = 512
    int ecnt = bucket_cnt[b];
    const int* bp = buckets + (size_t)b * BIN_CAP;

    // zero x3 (replaces memset dispatch; build precedes gather2)
    size_t u64 = (size_t)U * 64;
    for (size_t i = (size_t)b * BSIZE + tid; i < u64; i += (size_t)gridDim.x * BSIZE)
        x3[i] = 0.0f;

    cnt[tid] = 0;
    cur[tid] = 0;
    __syncthreads();

    // histogram + stage bucket into LDS (single global read)
    for (int i = tid; i < ecnt; i += BSIZE) {
        int e = bp[i];
        stage[i] = e;
        atomicAdd(&cnt[e & (BSIZE - 1)], 1);
    }
    __syncthreads();

    // local exclusive scan of padded row lengths
    int d = cnt[tid];
    int p = (d + 7) & ~7;
    sc[tid] = p;
    __syncthreads();
    for (int off = 1; off < BSIZE; off <<= 1) {
        int t = (tid >= off) ? sc[tid - off] : 0;
        __syncthreads();
        sc[tid] += t;
        __syncthreads();
    }
    int rstart = sc[tid] - p;           // local start of this thread's row

    // per-node finalize: rd, tail-zero, aldr1, seg
    int gb = b * CAPP;
    int n  = b * BSIZE + tid;
    if (n < N) {
        rd[n] = make_int2(gb + rstart, d);
        for (int k = d; k < p; k++) srcs[gb + rstart + k] = 0;
        float dv = 1.0f / sqrtf((float)d + 1.0f);   // +1 self-loop
        aldr1[n] = make_float4(al[n], dv, ar[n], 0.0f);

        int lo = 0, hi = U;             // first offs[] entry > n
        while (lo < hi) {
            int mid = (lo + hi) >> 1;
            if (offs[mid] <= n) lo = mid + 1; else hi = mid;
        }
        seg[n] = min(max(lo - 1, 0), U - 1);
    }
    __syncthreads();

    // fill srcs from LDS stage via LDS cursors
    for (int i = tid; i < ecnt; i += BSIZE) {
        int e = stage[i];
        int r = e & (BSIZE - 1);
        int o = atomicAdd(&cur[r], 1);
        int rs = sc[r] - ((cnt[r] + 7) & ~7);
        srcs[gb + rs + o] = e >> BSHIFT;
    }
}

// ---------------------------------------------------------------------------
// K5 (r28): gather layer 1, WAVE-PER-8-NODE-CHUNK + lane-parallel in-wave
// alpha. 8 independent rows per wave deepen the hiding of the per-row alpha
// chain and the serial epilogue (g1 was 4 us slower than g2 at chunk=4).
// rd[n] int2 and aldr float4 cut per-node scalar loads. The per-lane alpha
// gather reads only the leading float2 of aldr (8B, same line traffic).
// ---------------------------------------------------------------------------
__global__ void k_gather1(const int* __restrict__ srcs,
                          const int2* __restrict__ rd,
                          const unsigned short* __restrict__ xb,
                          const float4* __restrict__ aldr1,
                          const float* __restrict__ att_l, const float* __restrict__ att_r,
                          unsigned short* __restrict__ h1b, float4* __restrict__ aldr2,
                          int N)
{
    int lane = threadIdx.x & 63;
    int c0   = __builtin_amdgcn_readfirstlane(blockIdx.x * 4 + (threadIdx.x >> 6)) * CHUNK;
    if (c0 >= N) return;
    int nend = min(c0 + CHUNK, N);

    float atl = att_l[lane];
    float atr = att_r[lane];

    for (int n = c0; n < nend; n++) {
        int2   rdn  = rd[n];            // {row_start, deg}, one 8B scalar load
        int    s0   = rdn.x;
        int    cnt  = rdn.y;
        int    cntp = (cnt + 7) & ~7;
        float4 self = aldr1[n];         // {al, dinv, ar, _}, one 16B scalar load
        float  di   = self.y;
        float  arn  = self.z;

        float acc = 0.0f;
        for (int jb = 0; jb < cntp; jb += 64) {
            // Phase 1: lane-parallel alpha for edges [jb, jb+64)
            float a = 0.0f;
            int   e = jb + lane;
            if (e < cnt) {
                int s = srcs[s0 + e];               // coalesced vector load
                float2 as = *(const float2*)&aldr1[s];  // per-lane 8B gather, L2
                a = fast_tanh(as.x + arn) * as.y * di;
            }
            int te = min(cntp - jb, 64);
            // Phase 2: scalar-offload row gather, alpha via broadcast shfl
            for (int j = 0; j < te; j += 8) {
                int sv[8]; float vv[8];
                #pragma unroll
                for (int t = 0; t < 8; t++) sv[t] = srcs[s0 + jb + j + t];  // scalar
                #pragma unroll
                for (int t = 0; t < 8; t++) vv[t] = bf2f(xb[(size_t)sv[t] * 64 + lane]);
                #pragma unroll
                for (int t = 0; t < 8; t++) acc = fmaf(vv[t], __shfl(a, j + t), acc);
            }
        }

        float selfa = fast_tanh(self.x + arn) * di * di;
        float xnl   = bf2f(xb[(size_t)n * 64 + lane]);
        float v     = acc + (selfa + EPS) * xnl;

        float pl = v * atl;
        float pr = v * atr;
        #pragma unroll
        for (int off = 32; off > 0; off >>= 1) {
            pl += __shfl_down(pl, off);
            pr += __shfl_down(pr, off);
        }
        h1b[(size_t)n * 64 + lane] = f2bf(v);
        if (lane == 0) aldr2[n] = make_float4(pl, di, pr, 0.0f);
    }
}

// ---------------------------------------------------------------------------
// K6 (r28): gather layer 2, wave-per-8-node-chunk with register pooling +
// segment-boundary atomic flush + lane-parallel in-wave alpha. Halved wave
// count also cuts total atomic flushes ~65k -> ~42k.
// ---------------------------------------------------------------------------
__global__ void k_gather2(const int* __restrict__ srcs,
                          const int2* __restrict__ rd,
                          const unsigned short* __restrict__ h1b,
                          const unsigned short* __restrict__ xb,
                          const float4* __restrict__ aldr2,
                          const int* __restrict__ seg,
                          float* __restrict__ x3, int N)
{
    int lane = threadIdx.x & 63;
    int c0   = __builtin_amdgcn_readfirstlane(blockIdx.x * 4 + (threadIdx.x >> 6)) * CHUNK;
    if (c0 >= N) return;
    int nend = min(c0 + CHUNK, N);

    float uacc = 0.0f;
    int   useg = seg[c0];           // wave-uniform

    for (int n = c0; n < nend; n++) {
        int sg = seg[n];            // wave-uniform scalar load
        if (sg != useg) {
            atomicAdd(&x3[(size_t)useg * 64 + lane], uacc);
            uacc = 0.0f;
            useg = sg;
        }

        int2   rdn  = rd[n];
        int    s0   = rdn.x;
        int    cnt  = rdn.y;
        int    cntp = (cnt + 7) & ~7;
        float4 self = aldr2[n];     // {al2, dinv, ar2, _}
        float  di   = self.y;
        float  arn  = self.z;

        float acc = 0.0f;
        for (int jb = 0; jb < cntp; jb += 64) {
            float a = 0.0f;
            int   e = jb + lane;
            if (e < cnt) {
                int s = srcs[s0 + e];
                float2 as = *(const float2*)&aldr2[s];
                a = fast_tanh(as.x + arn) * as.y * di;
            }
            int te = min(cntp - jb, 64);
            for (int j = 0; j < te; j += 8) {
                int sv[8]; float vv[8];
                #pragma unroll
                for (int t = 0; t < 8; t++) sv[t] = srcs[s0 + jb + j + t];
                #pragma unroll
                for (int t = 0; t < 8; t++) vv[t] = bf2f(h1b[(size_t)sv[t] * 64 + lane]);
                #pragma unroll
                for (int t = 0; t < 8; t++) acc = fmaf(vv[t], __shfl(a, j + t), acc);
            }
        }

        float selfa = fast_tanh(self.x + arn) * di * di;
        float h1l   = bf2f(h1b[(size_t)n * 64 + lane]);
        float xnl   = bf2f(xb[(size_t)n * 64 + lane]);
        float v = acc + selfa * h1l + EPS * xnl;
        uacc += sqrtf(v * v + 1e-8f);
    }
    atomicAdd(&x3[(size_t)useg * 64 + lane], uacc);
}

// ---------------------------------------------------------------------------
// K8: head (r17 rewrite — 32 register accumulators, weights in LDS).
// ---------------------------------------------------------------------------
__global__ void __launch_bounds__(256)
k_head(const float* __restrict__ x3, const int* __restrict__ re_index,
       const float* __restrict__ W_f1, const float* __restrict__ b_f1,
       const float* __restrict__ W_lab, const float* __restrict__ b_lab,
       float* __restrict__ out, int U)
{
    __shared__ float wf[64][32];    // W_f1 staged: wf[k][j]
    __shared__ float wl[32][2];     // W_lab staged

    int tid = threadIdx.x;
    for (int i = tid; i < 64 * 32; i += 256) wf[i >> 5][i & 31] = W_f1[i];
    if (tid < 64) wl[tid >> 1][tid & 1] = W_lab[tid];
    __syncthreads();

    int u = blockIdx.x * blockDim.x + tid;
    if (u >= U) return;

    int r = re_index[u];
    const float* y = x3 + (size_t)r * 64;

    float s[32];
    #pragma unroll
    for (int j = 0; j < 32; j++) s[j] = b_f1[j];

    for (int k = 0; k < 64; k++) {
        float yk = y[k];
        #pragma unroll
        for (int j = 0; j < 32; j++) s[j] = fmaf(yk, wf[k][j], s[j]);
    }

    float o0 = b_lab[0], o1 = b_lab[1];
    #pragma unroll
    for (int j = 0; j < 32; j++) {
        float t = LRELU(s[j]);
        o0 = fmaf(t, wl[j][0], o0);
        o1 = fmaf(t, wl[j][1], o1);
    }
    out[(size_t)u * 2 + 0] = o0;
    out[(size_t)u * 2 + 1] = o1;
}

// ---------------------------------------------------------------------------
extern "C" void kernel_launch(void* const* d_in, const int* in_sizes, int n_in,
                              void* d_out, int out_size, void* d_ws, size_t ws_size,
                              hipStream_t stream)
{
    const float* num_prop = (const float*)d_in[0];
    const float* cat_prop = (const float*)d_in[1];
    const int*   offs     = (const int*)d_in[2];
    const int*   edge     = (const int*)d_in[3];
    const int*   re_index = (const int*)d_in[4];
    const float* W_num    = (const float*)d_in[5];
    const float* b_num    = (const float*)d_in[6];
    const float* W_cat    = (const float*)d_in[7];
    const float* b_cat    = (const float*)d_in[8];
    const float* W_tog    = (const float*)d_in[9];
    const float* b_tog    = (const float*)d_in[10];
    const float* att_l    = (const float*)d_in[11];
    const float* att_r    = (const float*)d_in[12];
    const float* W_f1     = (const float*)d_in[13];
    const float* b_f1     = (const float*)d_in[14];
    const float* W_lab    = (const float*)d_in[15];
    const float* b_lab    = (const float*)d_in[16];

    const int N = in_sizes[0] / 20;
    const int E = in_sizes[3] / 2;
    const int U = in_sizes[4];

    const int* src = edge;       // edge_index[0]
    const int* dst = edge + E;   // edge_index[1]

    const int NB = (N + BSIZE - 1) >> BSHIFT;          // dst buckets

    // workspace carve-up (4-byte units; float4 16B-aligned by layout order)
    float* ws = (float*)d_ws;
    size_t off = 0;
    float4* aldr1 = (float4*)(ws + off); off += (size_t)N * 4;
    float4* aldr2 = (float4*)(ws + off); off += (size_t)N * 4;
    unsigned short* xb  = (unsigned short*)(ws + off); off += (size_t)N * 32;  // bf16 x
    unsigned short* h1b = (unsigned short*)(ws + off); off += (size_t)N * 32;  // bf16 h1
    int*    buckets = (int*)(ws + off); off += (size_t)NB * BIN_CAP;   // packed entries
    float*  al   = ws + off; off += N;
    float*  ar   = ws + off; off += N;
    float*  x3   = ws + off; off += (size_t)U * 64;
    unsigned short* Wb  = (unsigned short*)(ws + off); off += 2048;  // 4096 bf16
    unsigned short* Wb1 = (unsigned short*)(ws + off); off += 1024;  // 2048 bf16
    int2*   rd         = (int2*)(ws + off); off += (size_t)N * 2;
    int*    seg        = (int*)(ws + off); off += N;
    int*    bucket_cnt = (int*)(ws + off); off += NB;
    int*    srcs       = (int*)(ws + off); off += (size_t)NB * CAPP;

    const int nbC    = (N + 4 * CHUNK - 1) / (4 * CHUNK);   // 4 waves/block
    const int nbBin  = (E + BIN_EPB - 1) / BIN_EPB;
    const int nbFeat = (N + 127) / 128;     // 128-node feat blocks

    // pack weights + zero bucket_cnt
    k_prep<<<1, 256, 0, stream>>>(W_num, W_cat, W_tog, Wb, Wb1, bucket_cnt, NB);

    // fused feat (128-node) + bin: bin blocks first, feat fills the rest
    k_featbin<<<nbBin + nbFeat, 512, 0, stream>>>(num_prop, cat_prop, Wb1, b_num,
                                                  b_cat, Wb, b_tog, att_l, att_r,
                                                  xb, al, ar,
                                                  src, dst, bucket_cnt, buckets,
                                                  nbBin, N, E, NB);

    // fused CSR build (+ x3 zeroing, packed rd/aldr1)
    k_build<<<NB, BSIZE, 0, stream>>>(buckets, bucket_cnt, al, ar, offs, aldr1,
                                      rd, seg, srcs, x3, N, U);

    // ---- FAConv layer 1 (h = h0 = x): 8-node chunk, lane-parallel alpha ----
    k_gather1<<<nbC, 256, 0, stream>>>(srcs, rd, xb, aldr1,
                                       att_l, att_r, h1b, aldr2, N);

    // ---- FAConv layer 2 (h = h1, h0 = x): 8-node chunk, lane-parallel
    //      alpha + boundary-flush pooling ----
    k_gather2<<<nbC, 256, 0, stream>>>(srcs, rd, h1b, xb, aldr2, seg, x3, N);

    // ---- head (pooling fused into gather2) ----
    k_head<<<(U + 255) / 256, 256, 0, stream>>>(x3, re_index, W_f1, b_f1, W_lab, b_lab,
                                                (float*)d_out, U);
}

// Round 13
// 312.821 us; speedup vs baseline: 1.0668x; 1.0323x over previous
//
#include <hip/hip_runtime.h>
#include <hip/hip_bf16.h>

#define LRELU(v) ((v) > 0.0f ? (v) : 0.01f * (v))
#define EPS 0.1f

#define BSHIFT  9           // 512-node buckets -> NB ~391 buckets
#define BSIZE   512
#define BIN_EPB 2048        // edges per bin block
#define BIN_CAP 6144        // bucket capacity (expected ~4092, wide headroom)
#define CAPP    10240       // per-bucket padded srcs region: BIN_CAP + 512*7 = 9728 <= 10240
#define CHUNK   4           // nodes per wave (r28's 8 dropped occupancy 73->68%; revert)

typedef __attribute__((ext_vector_type(8))) short bf16x8;
typedef __attribute__((ext_vector_type(4))) float f32x4;

// fast tanh via v_exp_f32 + v_rcp_f32: ~1e-7 abs err, saturates correctly
__device__ __forceinline__ float fast_tanh(float v)
{
    float e = __expf(2.0f * v);
    return 1.0f - 2.0f * __builtin_amdgcn_rcpf(e + 1.0f);
}

__device__ __forceinline__ float bf2f(unsigned short h)
{
    return __uint_as_float(((unsigned int)h) << 16);
}
__device__ __forceinline__ unsigned short f2bf(float f)
{
    unsigned int u = __float_as_uint(f);
    u += 0x7FFFu + ((u >> 16) & 1u);
    return (unsigned short)(u >> 16);
}

// ---------------------------------------------------------------------------
// K0: pack weights into bf16 MFMA B-fragment order (r15/r16-verified).
// Also zeroes bucket_cnt (runs before featbin; kills one memset dispatch).
// ---------------------------------------------------------------------------
__global__ void k_prep(const float* __restrict__ W_num, const float* __restrict__ W_cat,
                       const float* __restrict__ W_tog,
                       unsigned short* __restrict__ Wb, unsigned short* __restrict__ Wb1,
                       int* __restrict__ bucket_cnt, int NB)
{
    int t = threadIdx.x;            // one block, 256 threads
    for (int i = t; i < NB; i += 256) bucket_cnt[i] = 0;
    for (int i = t; i < 8 * 512; i += 256) {
        int tile = i >> 9;          // kt*4+nt
        int kt   = tile >> 2, nt = tile & 3;
        int lane = (i >> 3) & 63;
        int j    = i & 7;
        int k    = kt * 32 + (lane >> 4) * 8 + j;
        int n    = nt * 16 + (lane & 15);
        Wb[i] = f2bf(W_tog[k * 64 + n]);
    }
    for (int i = t; i < 4 * 512; i += 256) {
        int nt   = i >> 9;
        int lane = (i >> 3) & 63;
        int j    = i & 7;
        int k    = (lane >> 4) * 8 + j;     // 0..31
        int n    = nt * 16 + (lane & 15);   // 0..63
        float w;
        if (n < 32) w = (k < 20)  ? W_num[k * 32 + n]              : 0.0f;
        else        w = (k >= 20) ? W_cat[(k - 20) * 32 + (n - 32)] : 0.0f;
        Wb1[i] = f2bf(w);
    }
}

// ---------------------------------------------------------------------------
// K1+K2 (r27, kept): FUSED heterogeneous-grid kernel — bin blocks first,
// feat (128-node / 8-wave) blocks fill the remaining slots and overlap.
// ---------------------------------------------------------------------------
__global__ void __launch_bounds__(512)
k_featbin(// feat args
          const float* __restrict__ num_prop, const float* __restrict__ cat_prop,
          const unsigned short* __restrict__ Wb1, const float* __restrict__ b_num,
          const float* __restrict__ b_cat, const unsigned short* __restrict__ Wb,
          const float* __restrict__ b_tog, const float* __restrict__ att_l,
          const float* __restrict__ att_r, unsigned short* __restrict__ xb,
          float* __restrict__ al, float* __restrict__ ar,
          // bin args
          const int* __restrict__ src, const int* __restrict__ dst,
          int* __restrict__ bucket_cnt, int* __restrict__ buckets,
          int nbBin, int N, int E, int NB)
{
    __shared__ __align__(16) char shmem[28672];

    int tid = threadIdx.x;          // blockDim = 512

    if ((int)blockIdx.x < nbBin) {
        // ================= bin body =================
        int*  hist  = (int*)shmem;                  //  2 KB
        int*  lbase = hist + BSIZE;                 //  2 KB
        int*  gbase = lbase + BSIZE;                //  2 KB
        int2* stage = (int2*)(gbase + BSIZE);       // 16 KB

        int base = blockIdx.x * BIN_EPB;

        hist[tid] = 0;
        __syncthreads();

        int s[4], d[4], rk[4];
        #pragma unroll
        for (int k = 0; k < 4; k++) {
            int e = base + k * BSIZE + tid;
            s[k] = -1;
            if (e < E) {
                s[k] = src[e];
                d[k] = dst[e];
                rk[k] = atomicAdd(&hist[d[k] >> BSHIFT], 1);
            }
        }
        __syncthreads();

        int v = hist[tid];
        lbase[tid] = v;
        __syncthreads();
        for (int off = 1; off < BSIZE; off <<= 1) {
            int t = (tid >= off) ? lbase[tid - off] : 0;
            __syncthreads();
            lbase[tid] += t;
            __syncthreads();
        }
        int incl = lbase[tid];
        __syncthreads();
        lbase[tid] = incl - v;
        if (tid < NB && v > 0) gbase[tid] = atomicAdd(&bucket_cnt[tid], v);
        __syncthreads();

        #pragma unroll
        for (int k = 0; k < 4; k++) {
            if (s[k] >= 0) {
                int b = d[k] >> BSHIFT;
                stage[lbase[b] + rk[k]] = make_int2(s[k], d[k]);
            }
        }
        __syncthreads();

        int tot = min(BIN_EPB, E - base);
        for (int i = tid; i < tot; i += BSIZE) {
            int2 p = stage[i];
            int b = p.y >> BSHIFT;
            buckets[(size_t)b * BIN_CAP + gbase[b] + (i - lbase[b])] =
                (p.x << BSHIFT) | (p.y & (BSIZE - 1));
        }
    } else {
        // ================= feat body: 128 nodes, 8 waves =================
        unsigned short (*in_lds)[40] = (unsigned short(*)[40])shmem;            // 10.0 KB
        unsigned short (*mid)[72]    = (unsigned short(*)[72])(shmem + 10240);  // 18.4 KB

        int lane = tid & 63;
        int w    = tid >> 6;                        // wave 0..7
        int blockStart = (blockIdx.x - nbBin) * 128;

        for (int i = tid; i < 128 * 20; i += 512) {
            int node = i / 20, k = i % 20;
            int n = min(blockStart + node, N - 1);
            in_lds[node][k] = f2bf(num_prop[(size_t)n * 20 + k]);
        }
        for (int i = tid; i < 128 * 12; i += 512) {
            int node = i / 12, k = i % 12;
            int n = min(blockStart + node, N - 1);
            in_lds[node][20 + k] = f2bf(cat_prop[(size_t)n * 12 + k]);
        }
        __syncthreads();

        int q   = lane >> 4;
        int c16 = lane & 15;

        bf16x8 ain = *(const bf16x8*)&in_lds[w * 16 + c16][q * 8];
        #pragma unroll
        for (int nt = 0; nt < 4; nt++) {
            bf16x8 b = *(const bf16x8*)&Wb1[nt * 512 + lane * 8];
            f32x4 acc = {0.0f, 0.0f, 0.0f, 0.0f};
            acc = __builtin_amdgcn_mfma_f32_16x16x32_bf16(ain, b, acc, 0, 0, 0);
            int   ch   = nt * 16 + c16;
            float bias = (ch < 32) ? b_num[ch] : b_cat[ch - 32];
            #pragma unroll
            for (int r = 0; r < 4; r++) {
                float s = acc[r] + bias;
                s = LRELU(s);
                mid[w * 16 + q * 4 + r][ch] = f2bf(s);
            }
        }
        // intra-wave LDS dependency only (wave w writes/reads rows w*16..w*16+15)

        bf16x8 a0 = *(const bf16x8*)&mid[w * 16 + c16][q * 8];
        bf16x8 a1 = *(const bf16x8*)&mid[w * 16 + c16][32 + q * 8];

        float pal[4] = {0, 0, 0, 0};
        float par[4] = {0, 0, 0, 0};

        #pragma unroll
        for (int nt = 0; nt < 4; nt++) {
            bf16x8 b0 = *(const bf16x8*)&Wb[(0 * 4 + nt) * 512 + lane * 8];
            bf16x8 b1 = *(const bf16x8*)&Wb[(1 * 4 + nt) * 512 + lane * 8];
            f32x4 acc = {0.0f, 0.0f, 0.0f, 0.0f};
            acc = __builtin_amdgcn_mfma_f32_16x16x32_bf16(a0, b0, acc, 0, 0, 0);
            acc = __builtin_amdgcn_mfma_f32_16x16x32_bf16(a1, b1, acc, 0, 0, 0);

            int   ch  = nt * 16 + c16;
            float bt  = b_tog[ch];
            float atl = att_l[ch];
            float atr = att_r[ch];
            #pragma unroll
            for (int r = 0; r < 4; r++) {
                float s = acc[r] + bt;
                s = LRELU(s);
                int n = blockStart + w * 16 + q * 4 + r;
                if (n < N) xb[(size_t)n * 64 + ch] = f2bf(s);
                pal[r] = fmaf(s, atl, pal[r]);
                par[r] = fmaf(s, atr, par[r]);
            }
        }

        #pragma unroll
        for (int r = 0; r < 4; r++) {
            float pl = pal[r], pr = par[r];
            #pragma unroll
            for (int off = 8; off > 0; off >>= 1) {
                pl += __shfl_xor(pl, off);
                pr += __shfl_xor(pr, off);
            }
            int n = blockStart + w * 16 + q * 4 + r;
            if (c16 == 0 && n < N) { al[n] = pl; ar[n] = pr; }
        }
    }
}

// ---------------------------------------------------------------------------
// K2b: FUSED CSR build — histogram + scan + per-node finalize + fill.
// r29: ald1 back to DENSE float2 (r28's float4 halved alpha-table line
// density: FETCH 139->170 MB, gather1 +5 us). rd int2 packing kept
// (scalar-path, line-density-neutral). Also zeroes x3.
// ---------------------------------------------------------------------------
__global__ void __launch_bounds__(512)
k_build(const int* __restrict__ buckets, const int* __restrict__ bucket_cnt,
        const float* __restrict__ al, const int* __restrict__ offs,
        float2* __restrict__ ald1,
        int2* __restrict__ rd, int* __restrict__ seg,
        int* __restrict__ srcs, float* __restrict__ x3, int N, int U)
{
    __shared__ int stage[BIN_CAP];      // 24 KB
    __shared__ int cnt[BSIZE];
    __shared__ int sc[BSIZE];
    __shared__ int cur[BSIZE];

    int b   = blockIdx.x;
    int tid = threadIdx.x;              // blockDim = 512
    int ecnt = bucket_cnt[b];
    const int* bp = buckets + (size_t)b * BIN_CAP;

    // zero x3 (replaces memset dispatch; build precedes gather2)
    size_t u64 = (size_t)U * 64;
    for (size_t i = (size_t)b * BSIZE + tid; i < u64; i += (size_t)gridDim.x * BSIZE)
        x3[i] = 0.0f;

    cnt[tid] = 0;
    cur[tid] = 0;
    __syncthreads();

    // histogram + stage bucket into LDS (single global read)
    for (int i = tid; i < ecnt; i += BSIZE) {
        int e = bp[i];
        stage[i] = e;
        atomicAdd(&cnt[e & (BSIZE - 1)], 1);
    }
    __syncthreads();

    // local exclusive scan of padded row lengths
    int d = cnt[tid];
    int p = (d + 7) & ~7;
    sc[tid] = p;
    __syncthreads();
    for (int off = 1; off < BSIZE; off <<= 1) {
        int t = (tid >= off) ? sc[tid - off] : 0;
        __syncthreads();
        sc[tid] += t;
        __syncthreads();
    }
    int rstart = sc[tid] - p;           // local start of this thread's row

    // per-node finalize: rd, tail-zero, ald1, seg
    int gb = b * CAPP;
    int n  = b * BSIZE + tid;
    if (n < N) {
        rd[n] = make_int2(gb + rstart, d);
        for (int k = d; k < p; k++) srcs[gb + rstart + k] = 0;
        float dv = 1.0f / sqrtf((float)d + 1.0f);   // +1 self-loop
        ald1[n] = make_float2(al[n], dv);

        int lo = 0, hi = U;             // first offs[] entry > n
        while (lo < hi) {
            int mid = (lo + hi) >> 1;
            if (offs[mid] <= n) lo = mid + 1; else hi = mid;
        }
        seg[n] = min(max(lo - 1, 0), U - 1);
    }
    __syncthreads();

    // fill srcs from LDS stage via LDS cursors
    for (int i = tid; i < ecnt; i += BSIZE) {
        int e = stage[i];
        int r = e & (BSIZE - 1);
        int o = atomicAdd(&cur[r], 1);
        int rs = sc[r] - ((cnt[r] + 7) & ~7);
        srcs[gb + rs + o] = e >> BSHIFT;
    }
}

// ---------------------------------------------------------------------------
// K5 (r29 = r27 form + rd packing): gather layer 1, wave-per-4-node-chunk +
// lane-parallel in-wave alpha over DENSE float2 ald (8B lines). The 4-row
// parallelism hides the per-row alpha chain (r22/r23/r24-proven).
// ---------------------------------------------------------------------------
__global__ void k_gather1(const int* __restrict__ srcs,
                          const int2* __restrict__ rd,
                          const unsigned short* __restrict__ xb,
                          const float2* __restrict__ ald1, const float* __restrict__ ar,
                          const float* __restrict__ att_l, const float* __restrict__ att_r,
                          unsigned short* __restrict__ h1b, float2* __restrict__ ald2,
                          float* __restrict__ ar2, int N)
{
    int lane = threadIdx.x & 63;
    int c0   = __builtin_amdgcn_readfirstlane(blockIdx.x * 4 + (threadIdx.x >> 6)) * CHUNK;
    if (c0 >= N) return;
    int nend = min(c0 + CHUNK, N);

    float atl = att_l[lane];
    float atr = att_r[lane];

    for (int n = c0; n < nend; n++) {
        int2   rdn  = rd[n];            // {row_start, deg}, one 8B scalar load
        int    s0   = rdn.x;
        int    cnt  = rdn.y;
        int    cntp = (cnt + 7) & ~7;
        float2 self = ald1[n];          // {al[n], dinv[n]}
        float  di   = self.y;
        float  arn  = ar[n];

        float acc = 0.0f;
        for (int jb = 0; jb < cntp; jb += 64) {
            // Phase 1: lane-parallel alpha for edges [jb, jb+64)
            float a = 0.0f;
            int   e = jb + lane;
            if (e < cnt) {
                int s = srcs[s0 + e];               // coalesced vector load
                float2 as = ald1[s];                // per-lane 8B gather, dense lines
                a = fast_tanh(as.x + arn) * as.y * di;
            }
            int te = min(cntp - jb, 64);
            // Phase 2: scalar-offload row gather, alpha via broadcast shfl
            for (int j = 0; j < te; j += 8) {
                int sv[8]; float vv[8];
                #pragma unroll
                for (int t = 0; t < 8; t++) sv[t] = srcs[s0 + jb + j + t];  // scalar
                #pragma unroll
                for (int t = 0; t < 8; t++) vv[t] = bf2f(xb[(size_t)sv[t] * 64 + lane]);
                #pragma unroll
                for (int t = 0; t < 8; t++) acc = fmaf(vv[t], __shfl(a, j + t), acc);
            }
        }

        float selfa = fast_tanh(self.x + arn) * di * di;
        float xnl   = bf2f(xb[(size_t)n * 64 + lane]);
        float v     = acc + (selfa + EPS) * xnl;

        float pl = v * atl;
        float pr = v * atr;
        #pragma unroll
        for (int off = 32; off > 0; off >>= 1) {
            pl += __shfl_down(pl, off);
            pr += __shfl_down(pr, off);
        }
        h1b[(size_t)n * 64 + lane] = f2bf(v);
        if (lane == 0) { ald2[n] = make_float2(pl, di); ar2[n] = pr; }
    }
}

// ---------------------------------------------------------------------------
// K6 (r29 = r27 form + rd packing): gather layer 2, wave-per-4-node-chunk,
// register pooling + segment-boundary atomic flush + lane-parallel alpha.
// ---------------------------------------------------------------------------
__global__ void k_gather2(const int* __restrict__ srcs,
                          const int2* __restrict__ rd,
                          const unsigned short* __restrict__ h1b,
                          const unsigned short* __restrict__ xb,
                          const float2* __restrict__ ald2, const float* __restrict__ ar2,
                          const int* __restrict__ seg,
                          float* __restrict__ x3, int N)
{
    int lane = threadIdx.x & 63;
    int c0   = __builtin_amdgcn_readfirstlane(blockIdx.x * 4 + (threadIdx.x >> 6)) * CHUNK;
    if (c0 >= N) return;
    int nend = min(c0 + CHUNK, N);

    float uacc = 0.0f;
    int   useg = seg[c0];           // wave-uniform

    for (int n = c0; n < nend; n++) {
        int sg = seg[n];            // wave-uniform scalar load
        if (sg != useg) {
            atomicAdd(&x3[(size_t)useg * 64 + lane], uacc);
            uacc = 0.0f;
            useg = sg;
        }

        int2   rdn  = rd[n];
        int    s0   = rdn.x;
        int    cnt  = rdn.y;
        int    cntp = (cnt + 7) & ~7;
        float2 self = ald2[n];      // {al2[n], dinv[n]}
        float  di   = self.y;
        float  arn  = ar2[n];

        float acc = 0.0f;
        for (int jb = 0; jb < cntp; jb += 64) {
            float a = 0.0f;
            int   e = jb + lane;
            if (e < cnt) {
                int s = srcs[s0 + e];
                float2 as = ald2[s];
                a = fast_tanh(as.x + arn) * as.y * di;
            }
            int te = min(cntp - jb, 64);
            for (int j = 0; j < te; j += 8) {
                int sv[8]; float vv[8];
                #pragma unroll
                for (int t = 0; t < 8; t++) sv[t] = srcs[s0 + jb + j + t];
                #pragma unroll
                for (int t = 0; t < 8; t++) vv[t] = bf2f(h1b[(size_t)sv[t] * 64 + lane]);
                #pragma unroll
                for (int t = 0; t < 8; t++) acc = fmaf(vv[t], __shfl(a, j + t), acc);
            }
        }

        float selfa = fast_tanh(self.x + arn) * di * di;
        float h1l   = bf2f(h1b[(size_t)n * 64 + lane]);
        float xnl   = bf2f(xb[(size_t)n * 64 + lane]);
        float v = acc + selfa * h1l + EPS * xnl;
        uacc += sqrtf(v * v + 1e-8f);
    }
    atomicAdd(&x3[(size_t)useg * 64 + lane], uacc);
}

// ---------------------------------------------------------------------------
// K8: head (r17 rewrite — 32 register accumulators, weights in LDS).
// ---------------------------------------------------------------------------
__global__ void __launch_bounds__(256)
k_head(const float* __restrict__ x3, const int* __restrict__ re_index,
       const float* __restrict__ W_f1, const float* __restrict__ b_f1,
       const float* __restrict__ W_lab, const float* __restrict__ b_lab,
       float* __restrict__ out, int U)
{
    __shared__ float wf[64][32];    // W_f1 staged: wf[k][j]
    __shared__ float wl[32][2];     // W_lab staged

    int tid = threadIdx.x;
    for (int i = tid; i < 64 * 32; i += 256) wf[i >> 5][i & 31] = W_f1[i];
    if (tid < 64) wl[tid >> 1][tid & 1] = W_lab[tid];
    __syncthreads();

    int u = blockIdx.x * blockDim.x + tid;
    if (u >= U) return;

    int r = re_index[u];
    const float* y = x3 + (size_t)r * 64;

    float s[32];
    #pragma unroll
    for (int j = 0; j < 32; j++) s[j] = b_f1[j];

    for (int k = 0; k < 64; k++) {
        float yk = y[k];
        #pragma unroll
        for (int j = 0; j < 32; j++) s[j] = fmaf(yk, wf[k][j], s[j]);
    }

    float o0 = b_lab[0], o1 = b_lab[1];
    #pragma unroll
    for (int j = 0; j < 32; j++) {
        float t = LRELU(s[j]);
        o0 = fmaf(t, wl[j][0], o0);
        o1 = fmaf(t, wl[j][1], o1);
    }
    out[(size_t)u * 2 + 0] = o0;
    out[(size_t)u * 2 + 1] = o1;
}

// ---------------------------------------------------------------------------
extern "C" void kernel_launch(void* const* d_in, const int* in_sizes, int n_in,
                              void* d_out, int out_size, void* d_ws, size_t ws_size,
                              hipStream_t stream)
{
    const float* num_prop = (const float*)d_in[0];
    const float* cat_prop = (const float*)d_in[1];
    const int*   offs     = (const int*)d_in[2];
    const int*   edge     = (const int*)d_in[3];
    const int*   re_index = (const int*)d_in[4];
    const float* W_num    = (const float*)d_in[5];
    const float* b_num    = (const float*)d_in[6];
    const float* W_cat    = (const float*)d_in[7];
    const float* b_cat    = (const float*)d_in[8];
    const float* W_tog    = (const float*)d_in[9];
    const float* b_tog    = (const float*)d_in[10];
    const float* att_l    = (const float*)d_in[11];
    const float* att_r    = (const float*)d_in[12];
    const float* W_f1     = (const float*)d_in[13];
    const float* b_f1     = (const float*)d_in[14];
    const float* W_lab    = (const float*)d_in[15];
    const float* b_lab    = (const float*)d_in[16];

    const int N = in_sizes[0] / 20;
    const int E = in_sizes[3] / 2;
    const int U = in_sizes[4];

    const int* src = edge;       // edge_index[0]
    const int* dst = edge + E;   // edge_index[1]

    const int NB = (N + BSIZE - 1) >> BSHIFT;          // dst buckets

    // workspace carve-up (4-byte units; float2/int2 8B-aligned by layout)
    float* ws = (float*)d_ws;
    size_t off = 0;
    float2* ald1 = (float2*)(ws + off); off += (size_t)N * 2;
    float2* ald2 = (float2*)(ws + off); off += (size_t)N * 2;
    int2*   rd   = (int2*)(ws + off); off += (size_t)N * 2;
    unsigned short* xb  = (unsigned short*)(ws + off); off += (size_t)N * 32;  // bf16 x
    unsigned short* h1b = (unsigned short*)(ws + off); off += (size_t)N * 32;  // bf16 h1
    int*    buckets = (int*)(ws + off); off += (size_t)NB * BIN_CAP;   // packed entries
    float*  al   = ws + off; off += N;
    float*  ar   = ws + off; off += N;
    float*  ar2  = ws + off; off += N;
    float*  x3   = ws + off; off += (size_t)U * 64;
    unsigned short* Wb  = (unsigned short*)(ws + off); off += 2048;  // 4096 bf16
    unsigned short* Wb1 = (unsigned short*)(ws + off); off += 1024;  // 2048 bf16
    int*    seg        = (int*)(ws + off); off += N;
    int*    bucket_cnt = (int*)(ws + off); off += NB;
    int*    srcs       = (int*)(ws + off); off += (size_t)NB * CAPP;

    const int nbC    = (N + 4 * CHUNK - 1) / (4 * CHUNK);   // 4 waves/block
    const int nbBin  = (E + BIN_EPB - 1) / BIN_EPB;
    const int nbFeat = (N + 127) / 128;     // 128-node feat blocks

    // pack weights + zero bucket_cnt
    k_prep<<<1, 256, 0, stream>>>(W_num, W_cat, W_tog, Wb, Wb1, bucket_cnt, NB);

    // fused feat (128-node) + bin: bin blocks first, feat fills the rest
    k_featbin<<<nbBin + nbFeat, 512, 0, stream>>>(num_prop, cat_prop, Wb1, b_num,
                                                  b_cat, Wb, b_tog, att_l, att_r,
                                                  xb, al, ar,
                                                  src, dst, bucket_cnt, buckets,
                                                  nbBin, N, E, NB);

    // fused CSR build (+ x3 zeroing, packed rd, dense float2 ald1)
    k_build<<<NB, BSIZE, 0, stream>>>(buckets, bucket_cnt, al, offs, ald1,
                                      rd, seg, srcs, x3, N, U);

    // ---- FAConv layer 1 (h = h0 = x): 4-node chunk, lane-parallel alpha ----
    k_gather1<<<nbC, 256, 0, stream>>>(srcs, rd, xb, ald1, ar,
                                       att_l, att_r, h1b, ald2, ar2, N);

    // ---- FAConv layer 2 (h = h1, h0 = x): 4-node chunk, lane-parallel
    //      alpha + boundary-flush pooling ----
    k_gather2<<<nbC, 256, 0, stream>>>(srcs, rd, h1b, xb, ald2, ar2, seg, x3, N);

    // ---- head (pooling fused into gather2) ----
    k_head<<<(U + 255) / 256, 256, 0, stream>>>(x3, re_index, W_f1, b_f1, W_lab, b_lab,
                                                (float*)d_out, U);
}